// Round 7
// baseline (426.826 us; speedup 1.0000x reference)
//
#include <hip/hip_runtime.h>

// PostNormBoth R6 = R1 shape (256 blocks x 512 thr, b=2 cols, 8 waves) with:
//  - s_v row stride 272 bf16 -> parity-split B-frag reads are <=2-way (free).
//  - tanh+LN-partials computed in-place on MFMA accumulators (all D cols are
//    exact parity duplicates, no garbage) -> 2 barriers/step instead of 3.
//  - Cross-wave LN stats via LDS atomicAdd into double-buffered s_red[2][4].
//  - Sliding-window register memory; s_mem needs no zero-init (admit gate).

#define TT 256

typedef __bf16 bf16x8 __attribute__((ext_vector_type(8)));
typedef float  f32x4  __attribute__((ext_vector_type(4)));

__device__ __forceinline__ float fast_tanh(float x) {
    float e = __expf(2.f * x);
    return 1.f - __fdividef(2.f, e + 1.f);
}

template<int CTRL, int RM>
__device__ __forceinline__ float dpp_add(float v) {
    int t = __builtin_amdgcn_update_dpp(0, __float_as_int(v), CTRL, RM, 0xf, true);
    return v + __int_as_float(t);
}
// full 64-lane sum; valid in lane 63 (output epilogue only)
__device__ __forceinline__ float wave_sum63(float v) {
    v = dpp_add<0xB1,  0xf>(v);
    v = dpp_add<0x4E,  0xf>(v);
    v = dpp_add<0x141, 0xf>(v);
    v = dpp_add<0x140, 0xf>(v);
    v = dpp_add<0x142, 0xa>(v);
    v = dpp_add<0x143, 0xc>(v);
    return v;
}

// gaussian-attention weights for wave-uniform pointer p (TAU=8, K=2, SLOTS=64)
__device__ __forceinline__ void attn_w(int p, float w[5]) {
    float s = 0.f;
    #pragma unroll
    for (int k = 0; k < 5; ++k) {
        int idx = (p + k - 2) & 63;
        float d = (float)(idx - p);
        w[k] = expf(-(d * d) * 0.125f);
        s += w[k];
    }
    float inv = 1.f / s;
    #pragma unroll
    for (int k = 0; k < 5; ++k) w[k] *= inv;
}

// ---- dynamic LDS layout (bytes) ----
// s_mem [2][64][256] f32 :      0 (131072)  no zero-init needed (admit gate)
// s_yt  [2][256]     f32 : 131072 (2048)
// s_x   [2][256]     f32 : 133120 (2048)
// s_v   [2][272]    bf16 : 135168 (1088)    stride 272 kills parity aliasing
// s_red [2][4]       f32 : 136256 (32)      double-buffered {s1c0,s1c1,s2c0,s2c1}
// s_oacc[20]         f32 : 136288 (80)
#define SMEM_BYTES 136368

__global__ __launch_bounds__(512, 2)
void postnorm_kernel(const float* __restrict__ x,
                     const float* __restrict__ W_embed,
                     const float* __restrict__ b_embed,
                     const float* __restrict__ W_update,
                     const float* __restrict__ b_update,
                     const float* __restrict__ gamma,
                     const float* __restrict__ beta,
                     const float* __restrict__ W_out,
                     const float* __restrict__ b_out,
                     const float* __restrict__ ctx_s,
                     float* __restrict__ out)
{
    extern __shared__ __align__(16) char smem[];
    float*  s_mem  = (float*)(smem);
    float*  s_yt   = (float*)(smem + 131072);
    float*  s_x    = (float*)(smem + 133120);
    __bf16* s_v    = (__bf16*)(smem + 135168);
    float*  s_red  = (float*)(smem + 136256);
    float*  s_oacc = (float*)(smem + 136288);

    const int tid  = threadIdx.x;   // 0..511
    const int n    = tid >> 8;      // batch row (thread role)
    const int i    = tid & 255;     // hidden index (thread role)
    const int w    = tid >> 6;      // wave 0..7, owns W rows [32w, 32w+32)
    const int lane = tid & 63;
    const int bn   = lane & 15;     // MFMA col; D col c == y[row c&1]
    const int quad = lane >> 4;
    const int r0   = blockIdx.x * 2;

    s_x[tid] = x[(r0 + n) * TT + i];
    if (tid < 20) s_oacc[tid] = 0.f;
    if (tid < 8)  s_red[tid]  = 0.f;

    const float we  = W_embed[i];
    const float be  = b_embed[i];
    const float gm  = gamma[i];
    const float btt = beta[i];
    const float cs  = 1.f / (1.f + expf(-ctx_s[0]));

    float Wi[5];
    attn_w(30, Wi);                       // interior (p in [2,61] identical)
    float wt0, wt1, wt2, wt3, wt4;
    {   float t0[5]; attn_w(0, t0);       // pointer 0 (edge) for t=0
        wt0 = t0[0]; wt1 = t0[1]; wt2 = t0[2]; wt3 = t0[3]; wt4 = t0[4];
    }

    // per-lane bias for rows w*32 + {0,16} + quad*4 + e (same for all cols)
    const f32x4 bu0 = *(const f32x4*)(b_update + w * 32 + quad * 4);
    const f32x4 bu1 = *(const f32x4*)(b_update + w * 32 + 16 + quad * 4);

    // ---- W_update rows [32w..32w+32) -> bf16 A-frags in regs ----
    bf16x8 wfa[2][8];
    #pragma unroll
    for (int mt = 0; mt < 2; ++mt) {
        #pragma unroll
        for (int kt = 0; kt < 8; ++kt) {
            const float* wp = W_update + (w * 32 + mt * 16 + bn) * 256
                                       + kt * 32 + quad * 8;
            f32x4 a = *(const f32x4*)wp;
            f32x4 b = *(const f32x4*)(wp + 4);
            bf16x8 f;
            f[0] = (__bf16)a[0]; f[1] = (__bf16)a[1];
            f[2] = (__bf16)a[2]; f[3] = (__bf16)a[3];
            f[4] = (__bf16)b[0]; f[5] = (__bf16)b[1];
            f[6] = (__bf16)b[2]; f[7] = (__bf16)b[3];
            wfa[mt][kt] = f;
        }
    }

    __syncthreads();
    {   // v(0): memory==0, h==0 -> v = inp(0)
        float inp = fast_tanh(s_x[n << 8] * we + be);
        s_v[n * 272 + i] = (__bf16)inp;
    }
    __syncthreads();

    float hn = 0.f;
    float w0 = 0.f, w1 = 0.f, w2 = 0.f, w3 = 0.f, w4 = 0.f; // slots t-2..t+2
    float* mcol = s_mem + (n << 14) + i;
    const __bf16* vsrc = s_v + (bn & 1) * 272 + quad * 8;

    #pragma unroll 1
    for (int t = 0; t < TT; ++t) {
        const int tn = (t < TT - 1) ? t + 1 : TT - 1;
        // --- prefetches (cover under MFMA). Slot (t+3)&63 untouched until
        // t==59 => gate to exact zero (also makes s_mem init-free). ---
        float admld = mcol[((t + 3) & 63) << 8];
        float adm   = (t >= 59) ? admld : 0.f;
        float xn    = s_x[(n << 8) + tn];
        float nw0, nw1, nw2, nw3, nw4;
        {   int pn = tn & 63;                    // wave-uniform
            if (pn >= 2 && pn <= 61) {
                nw0 = Wi[0]; nw1 = Wi[1]; nw2 = Wi[2]; nw3 = Wi[3]; nw4 = Wi[4];
            } else {
                float tmp[5]; attn_w(pn, tmp);
                nw0 = tmp[0]; nw1 = tmp[1]; nw2 = tmp[2]; nw3 = tmp[3]; nw4 = tmp[4];
            }
        }

        // --- P1: MFMA (2 indep 8-chains) ---
        f32x4 acc0 = {0,0,0,0}, acc1 = {0,0,0,0};
        #pragma unroll
        for (int kt = 0; kt < 8; ++kt) {
            bf16x8 bfr = *(const bf16x8*)(vsrc + kt * 32);
            acc0 = __builtin_amdgcn_mfma_f32_16x16x32_bf16(wfa[0][kt], bfr, acc0, 0, 0, 0);
            acc1 = __builtin_amdgcn_mfma_f32_16x16x32_bf16(wfa[1][kt], bfr, acc1, 0, 0, 0);
        }
        // in-place tanh + LN partial stats (cols are parity duplicates)
        f32x4 ty0, ty1;
        float s1 = 0.f, s2 = 0.f;
        #pragma unroll
        for (int e = 0; e < 4; ++e) {
            ty0[e] = fast_tanh(acc0[e] + bu0[e]);
            ty1[e] = fast_tanh(acc1[e] + bu1[e]);
            s1 += ty0[e] + ty1[e];
            s2 += ty0[e]*ty0[e] + ty1[e]*ty1[e];
        }
        // sum over quads (xor 16/32 preserves bn); lanes 0/1 = col0/col1
        s1 += __shfl_xor(s1, 16, 64); s1 += __shfl_xor(s1, 32, 64);
        s2 += __shfl_xor(s2, 16, 64); s2 += __shfl_xor(s2, 32, 64);
        if (lane < 2) {
            atomicAdd(&s_red[(t & 1) * 4 + lane], s1);
            atomicAdd(&s_red[(t & 1) * 4 + 2 + lane], s2);
        }
        if (bn < 2) {
            float* yb = s_yt + bn * 256 + w * 32 + quad * 4;
            *(f32x4*)(yb)      = ty0;
            *(f32x4*)(yb + 16) = ty1;
        }
        __syncthreads();   // A

        // --- P2: LN finalize + window scatter/gather + v(t+1) ---
        f32x4 red = *(const f32x4*)(s_red + (t & 1) * 4);   // broadcast 16B
        float yt  = s_yt[tid];
        if (tid < 4) s_red[((t + 1) & 1) * 4 + tid] = 0.f;  // zero other buf
        float S1 = (n == 0) ? red[0] : red[1];
        float S2 = (n == 0) ? red[2] : red[3];
        float mu   = S1 * (1.f / 256.f);
        float var  = S2 * (1.f / 256.f) - mu * mu;
        float rstd = rsqrtf(var + 1e-5f);
        hn = (yt - mu) * rstd * gm + btt;

        w0 += wt0*hn; w1 += wt1*hn; w2 += wt2*hn; w3 += wt3*hn; w4 += wt4*hn;

        if (t < TT - 1) {
            mcol[((t - 2) & 63) << 8] = w0;      // retire slot t-2
            w0 = w1; w1 = w2; w2 = w3; w3 = w4; w4 = adm;
            float ctx = ((nw0*w0 + nw1*w1) + (nw2*w2 + nw3*w3)) + nw4*w4;
            float inp = fast_tanh(xn * we + be);
            float v = inp + cs * ctx + hn;
            s_v[n * 272 + i] = (__bf16)v;
            wt0 = nw0; wt1 = nw1; wt2 = nw2; wt3 = nw3; wt4 = nw4;
        }
        __syncthreads();   // B
    }

    // --- epilogue: out[r0+n, o] = h_n . W_out[o,:] + b_out[o] ---
    #pragma unroll
    for (int o = 0; o < 10; ++o) {
        float p = wave_sum63(hn * W_out[o * 256 + i]);   // n wave-uniform
        if (lane == 63) atomicAdd(&s_oacc[n * 10 + o], p);
    }
    __syncthreads();
    if (tid < 20) {
        int nn = tid / 10, o = tid % 10;
        out[(r0 + nn) * 10 + o] = s_oacc[tid] + b_out[o];
    }
}

extern "C" void kernel_launch(void* const* d_in, const int* in_sizes, int n_in,
                              void* d_out, int out_size, void* d_ws, size_t ws_size,
                              hipStream_t stream) {
    const float* x    = (const float*)d_in[0];
    const float* W_e  = (const float*)d_in[1];
    const float* b_e  = (const float*)d_in[2];
    const float* W_u  = (const float*)d_in[3];
    const float* b_u  = (const float*)d_in[4];
    const float* gmm  = (const float*)d_in[5];
    const float* bta  = (const float*)d_in[6];
    const float* W_o  = (const float*)d_in[7];
    const float* b_o  = (const float*)d_in[8];
    const float* cst  = (const float*)d_in[9];
    float* out = (float*)d_out;

    (void)hipFuncSetAttribute(reinterpret_cast<const void*>(postnorm_kernel),
                              hipFuncAttributeMaxDynamicSharedMemorySize,
                              SMEM_BYTES);

    postnorm_kernel<<<dim3(256), dim3(512), SMEM_BYTES, stream>>>(
        x, W_e, b_e, W_u, b_u, gmm, bta, W_o, b_o, cst, out);
}